// Round 3
// baseline (3799.414 us; speedup 1.0000x reference)
//
#include <hip/hip_runtime.h>

#define B_ 64
#define T_ 512
#define D_ 1024
#define K_ 50
#define MROWS (B_ * T_)  // 32768

// ---------------------------------------------------------------------------
// Kernel 1: emissions GEMM. BM=128 rows, split-K (SK from ws_size, target 4).
// grid (256, SK), 256 threads. Per-thread 2 rows x 13 cols = 26 acc VGPRs
// (NO min-waves launch-bounds clamp — R2's VGPR=64 spill disaster).
// A staged in LDS with quad-XOR swizzle (conflict-free b128 reads);
// W chunk in LDS [c][k], reads are wave-uniform broadcasts (never conflict).
// Partials stored TRANSPOSED P[sk][c][row] -> coalesced stores.
// ---------------------------------------------------------------------------
__global__ __launch_bounds__(256) void gemm_kernel(const float* __restrict__ A,
                                                   const float* __restrict__ W,
                                                   float* __restrict__ P,
                                                   int chunkK) {
  __shared__ float As[128][20];  // 16 data + 4 pad dwords; quads swizzled
  __shared__ float Wt[52][20];   // [c][k], cols padded 50->52

  const int tid = threadIdx.x;
  const int rowBase = blockIdx.x * 128;
  const int kBase = blockIdx.y * chunkK;
  float* __restrict__ Pp = P + (size_t)blockIdx.y * K_ * MROWS;

  const int rg = tid & 63;
  const int cg = tid >> 6;
  const int c0 = cg * 13;
  const int swr = (rg >> 3) & 3;

  float acc[2][13];
#pragma unroll
  for (int i = 0; i < 2; i++)
#pragma unroll
    for (int j = 0; j < 13; j++) acc[i][j] = 0.f;

  const int q = tid & 3;
  const int rr = tid >> 2;

  const int iters = chunkK >> 4;
  for (int ch = 0; ch < iters; ++ch) {
    const int kb = kBase + (ch << 4);
    // stage A tile (128 rows x 16 k), quad-swizzled
#pragma unroll
    for (int s = 0; s < 2; s++) {
      const int r = rr + 64 * s;
      const float4 v = *(const float4*)&A[(size_t)(rowBase + r) * 1024 + kb + q * 4];
      const int p = (q + ((r >> 3) & 3)) & 3;
      *(float4*)&As[r][p * 4] = v;
    }
    // stage W chunk (16 k x 50 c) -> Wt[c][k]
#pragma unroll
    for (int s = 0; s < 4; s++) {
      const int l = tid + 256 * s;
      if (l < 832) {
        const int kk = l / 52;
        const int c = l - kk * 52;
        Wt[c][kk] = (c < 50) ? W[(size_t)(kb + kk) * 50 + c] : 0.f;
      }
    }
    __syncthreads();
#pragma unroll
    for (int k4 = 0; k4 < 4; k4++) {
      const int pq = ((k4 + swr) & 3) * 4;
      const float4 a0 = *(const float4*)&As[rg][pq];
      const float4 a1 = *(const float4*)&As[rg + 64][pq];
#pragma unroll
      for (int j = 0; j < 13; j++) {
        const float4 w = *(const float4*)&Wt[c0 + j][k4 * 4];
        float t0 = acc[0][j], t1 = acc[1][j];
        t0 = fmaf(a0.x, w.x, t0); t1 = fmaf(a1.x, w.x, t1);
        t0 = fmaf(a0.y, w.y, t0); t1 = fmaf(a1.y, w.y, t1);
        t0 = fmaf(a0.z, w.z, t0); t1 = fmaf(a1.z, w.z, t1);
        t0 = fmaf(a0.w, w.w, t0); t1 = fmaf(a1.w, w.w, t1);
        acc[0][j] = t0; acc[1][j] = t1;
      }
    }
    __syncthreads();
  }
#pragma unroll
  for (int j = 0; j < 13; j++) {
    const int c = c0 + j;
    if (c < 50) {
      Pp[(size_t)c * MROWS + rowBase + rg] = acc[0][j];
      Pp[(size_t)c * MROWS + rowBase + rg + 64] = acc[1][j];
    }
  }
}

// ---------------------------------------------------------------------------
// Kernel 2: combine SK transposed partials + bias, LDS-transpose, apply mask,
// write row-major scores. Both global reads and writes coalesced.
// grid 256 blocks x 256 thr; each block does 128 rows x 50 cols.
// ---------------------------------------------------------------------------
__global__ __launch_bounds__(256) void combine_kernel(const float* __restrict__ P,
                                                      int SK,
                                                      const float* __restrict__ bias,
                                                      const int* __restrict__ mask,
                                                      float* __restrict__ scores,
                                                      float* __restrict__ lossSlot) {
  __shared__ float t_lds[128][53];
  const int tid = threadIdx.x;
  const int rowBase = blockIdx.x * 128;

#pragma unroll
  for (int p = 0; p < 25; p++) {
    const int idx = tid + 256 * p;  // 6400 = 50c x 128r
    const int c = idx >> 7;
    const int r = idx & 127;
    float s = 0.f;
    for (int sk = 0; sk < SK; sk++)
      s += P[(size_t)sk * K_ * MROWS + (size_t)c * MROWS + rowBase + r];
    t_lds[r][c] = s + bias[c];
  }
  __syncthreads();
#pragma unroll
  for (int p = 0; p < 25; p++) {
    const int o = tid + 256 * p;
    const int r = o / 50;
    const int c = o - r * 50;
    const float v = t_lds[r][c] * (float)mask[rowBase + r];
    scores[(size_t)rowBase * 50 + o] = v;
  }
  if (tid == 0 && blockIdx.x == 0) *lossSlot = 0.f;
}

// ---------------------------------------------------------------------------
// Kernel 3: CRF. grid (64,2), 256 threads.
//   y==0: wave0 runs the forward (log-partition) chain SINGLE-WAVE with no
//         barriers (LDS uniform-broadcast gather of e[j]); waves1-3 compute
//         gold-score partials concurrently; one barrier at the end; loss.
//   y==1: wave0 runs Viterbi single-wave (52-add + 51-node first-index
//         argmax tree per step), bp in LDS; then chunked backtrace (all thr).
// ---------------------------------------------------------------------------
__global__ __launch_bounds__(256) void crf_kernel(const float* __restrict__ scores,
                                                  const int* __restrict__ mask,
                                                  const int* __restrict__ labels,
                                                  const float* __restrict__ trans,
                                                  const float* __restrict__ startT,
                                                  const float* __restrict__ endT,
                                                  float* __restrict__ tagsOut,
                                                  float* __restrict__ lossSlot) {
  __shared__ float x_lds[64];
  __shared__ unsigned char bp_s[511 * 52];
  __shared__ unsigned char g_s[32 * 52];
  __shared__ unsigned char chin_s[32];
  __shared__ float redp_s[4];
  __shared__ int redm_s[4];
  __shared__ float logZ_s;
  __shared__ int last_s;

  const int b = blockIdx.x;
  const int tid = threadIdx.x;
  const int wave = tid >> 6;
  const int lane = tid & 63;
  const int k = lane;
  const int kc = (k < 50) ? k : 49;
  const size_t sb = (size_t)b * T_ * 50;
  const int bT = b * T_;

  if (blockIdx.y == 0) {
    // ================= forward + gold + loss =================
    if (wave == 0) {
      float eT[52];
#pragma unroll
      for (int j = 0; j < 52; j++)
        eT[j] = (j < 50) ? __expf(trans[j * 50 + kc]) : 0.f;
      float af = (k < 50) ? (startT[k] + scores[sb + k]) : -1e30f;
      float M = __int_as_float(__builtin_amdgcn_readfirstlane(__float_as_int(af)));
      float em0 = scores[sb + 50 + kc];
      float em1 = scores[sb + 100 + kc];
      int mk0 = mask[bT + 1];
      int mk1 = mask[bT + 2];
      for (int t = 1; t < T_; ++t) {
        const float emit = em0;
        const int mt = mk0;
        em0 = em1; mk0 = mk1;
        if (t + 2 < T_) {
          em1 = scores[sb + (size_t)(t + 2) * 50 + kc];
          mk1 = mask[bT + t + 2];
        }
        const float e = __expf(af - M);
        x_lds[lane] = e;  // same-wave DS ordering; no barrier needed
        float ev[52];
#pragma unroll
        for (int u = 0; u < 13; u++)
          *(float4*)&ev[4 * u] = *(const float4*)&x_lds[4 * u];
        float p0 = 0.f, p1 = 0.f, p2 = 0.f, p3 = 0.f;
#pragma unroll
        for (int u = 0; u < 13; u++) {
          p0 = fmaf(ev[4 * u + 0], eT[4 * u + 0], p0);
          p1 = fmaf(ev[4 * u + 1], eT[4 * u + 1], p1);
          p2 = fmaf(ev[4 * u + 2], eT[4 * u + 2], p2);
          p3 = fmaf(ev[4 * u + 3], eT[4 * u + 3], p3);
        }
        const float S = (p0 + p1) + (p2 + p3);
        const float afn = M + __logf(S) + emit;
        af = (mt > 0 && k < 50) ? afn : af;
        M = __int_as_float(__builtin_amdgcn_readfirstlane(__float_as_int(af)));
      }
      // logZ = LSE(af + end)
      const float x = (k < 50) ? (af + endT[k]) : -3e38f;
      float mx = x;
#pragma unroll
      for (int off = 32; off >= 1; off >>= 1) mx = fmaxf(mx, __shfl_xor(mx, off));
      float sm = (k < 50) ? __expf(x - mx) : 0.f;
#pragma unroll
      for (int off = 32; off >= 1; off >>= 1) sm += __shfl_xor(sm, off);
      if (lane == 0) logZ_s = mx + __logf(sm);
    } else {
      // gold partials on waves 1-3 (192 threads x 3 slices)
      float part = 0.f;
      int mcnt = 0;
#pragma unroll
      for (int s = 0; s < 3; s++) {
        const int t = (tid - 64) + 192 * s;
        if (t < T_) {
          const int lt = labels[bT + t];
          const int mt = mask[bT + t];
          mcnt += mt;
          if (mt > 0) part += scores[sb + (size_t)t * 50 + lt];
          if (t < T_ - 1) {
            const int ln = labels[bT + t + 1];
            const int mn = mask[bT + t + 1];
            if (mn > 0) part += trans[lt * 50 + ln];
          }
        }
      }
#pragma unroll
      for (int off = 32; off >= 1; off >>= 1) {
        part += __shfl_xor(part, off);
        mcnt += __shfl_xor(mcnt, off);
      }
      if (lane == 0) { redp_s[wave] = part; redm_s[wave] = mcnt; }
    }
    __syncthreads();
    if (tid == 0) {
      float gold = redp_s[1] + redp_s[2] + redp_s[3];
      const int tot = redm_s[1] + redm_s[2] + redm_s[3];
      const int l0 = labels[bT];
      const int llast = labels[bT + (tot - 1)];
      gold += startT[l0] + endT[llast];
      atomicAdd(lossSlot, -(gold - logZ_s));
    }
  } else {
    // ================= Viterbi =================
    if (wave == 0) {
      float Tv[52];
#pragma unroll
      for (int j = 0; j < 52; j++)
        Tv[j] = (j < 50) ? trans[j * 50 + kc] : -1e30f;
      float av = (k < 50) ? (startT[k] + scores[sb + k]) : -1e30f;
      float em0 = scores[sb + 50 + kc];
      float em1 = scores[sb + 100 + kc];
      int mk0 = mask[bT + 1];
      int mk1 = mask[bT + 2];
      for (int t = 1; t < T_; ++t) {
        const float emit = em0;
        const int mt = mk0;
        em0 = em1; mk0 = mk1;
        if (t + 2 < T_) {
          em1 = scores[sb + (size_t)(t + 2) * 50 + kc];
          mk1 = mask[bT + t + 2];
        }
        x_lds[lane] = av;
        float avv[52];
#pragma unroll
        for (int u = 0; u < 13; u++)
          *(float4*)&avv[4 * u] = *(const float4*)&x_lds[4 * u];
        float u0[52];
#pragma unroll
        for (int j = 0; j < 52; j++) u0[j] = avv[j] + Tv[j];
        // first-index argmax tree (strict > : second wins only if greater)
        float v1[26]; int i1[26];
#pragma unroll
        for (int j = 0; j < 26; j++) {
          const bool g = u0[2 * j + 1] > u0[2 * j];
          v1[j] = g ? u0[2 * j + 1] : u0[2 * j];
          i1[j] = g ? 2 * j + 1 : 2 * j;
        }
        float v2[13]; int i2[13];
#pragma unroll
        for (int j = 0; j < 13; j++) {
          const bool g = v1[2 * j + 1] > v1[2 * j];
          v2[j] = g ? v1[2 * j + 1] : v1[2 * j];
          i2[j] = g ? i1[2 * j + 1] : i1[2 * j];
        }
        float v3[7]; int i3[7];
#pragma unroll
        for (int j = 0; j < 6; j++) {
          const bool g = v2[2 * j + 1] > v2[2 * j];
          v3[j] = g ? v2[2 * j + 1] : v2[2 * j];
          i3[j] = g ? i2[2 * j + 1] : i2[2 * j];
        }
        v3[6] = v2[12]; i3[6] = i2[12];
        float v4[4]; int i4[4];
#pragma unroll
        for (int j = 0; j < 3; j++) {
          const bool g = v3[2 * j + 1] > v3[2 * j];
          v4[j] = g ? v3[2 * j + 1] : v3[2 * j];
          i4[j] = g ? i3[2 * j + 1] : i3[2 * j];
        }
        v4[3] = v3[6]; i4[3] = i3[6];
        const bool ga = v4[1] > v4[0];
        const float va = ga ? v4[1] : v4[0];
        const int ia = ga ? i4[1] : i4[0];
        const bool gb = v4[3] > v4[2];
        const float vb = gb ? v4[3] : v4[2];
        const int ib = gb ? i4[3] : i4[2];
        const bool gf = vb > va;
        const float best = gf ? vb : va;
        const int bi = gf ? ib : ia;

        if (k < 50) bp_s[(t - 1) * 52 + k] = (unsigned char)((mt > 0) ? bi : k);
        av = (mt > 0 && k < 50) ? (best + emit) : av;
      }
      // final argmax over lanes, first-index tie-break
      float x = (k < 50) ? (av + endT[k]) : -3e38f;
      int xi = (k < 50) ? k : 63;
#pragma unroll
      for (int off = 32; off >= 1; off >>= 1) {
        const float ov = __shfl_xor(x, off);
        const int oi = __shfl_xor(xi, off);
        if (ov > x || (ov == x && oi < xi)) { x = ov; xi = oi; }
      }
      if (lane == 0) last_s = xi;
    }
    __syncthreads();  // bp_s + last_s complete
    const int last = last_s;
    // phase A: compose 16-step chunks
    for (int p = 0; p < 7; p++) {
      const int idx = tid + 256 * p;
      if (idx < 1600) {
        const int c = idx / 50;
        const int s2 = idx - c * 50;
        int x2 = s2;
        const int lo = 16 * c;
        const int hi = min(16 * c + 15, 510);
        for (int i = hi; i >= lo; --i) x2 = bp_s[i * 52 + x2];
        g_s[c * 52 + s2] = (unsigned char)x2;
      }
    }
    __syncthreads();
    // phase B: serial chunk-boundary walk
    if (tid == 0) {
      int cur = last;
      chin_s[31] = (unsigned char)cur;
      for (int c = 31; c >= 1; --c) {
        cur = g_s[c * 52 + cur];
        chin_s[c - 1] = (unsigned char)cur;
      }
      const int m511 = mask[bT + 511];
      tagsOut[(size_t)bT + 511] = (float)((m511 > 0) ? last : 0);
    }
    __syncthreads();
    // phase C: per-chunk backtrace + tag stores
    if (tid < 32) {
      const int c = tid;
      int x3 = chin_s[c];
      const int lo = 16 * c;
      const int hi = min(16 * c + 15, 510);
      for (int i = hi; i >= lo; --i) {
        x3 = bp_s[i * 52 + x3];
        const int mi = mask[bT + i];
        tagsOut[(size_t)bT + i] = (float)((mi > 0) ? x3 : 0);
      }
    }
  }
}

// ---------------------------------------------------------------------------
extern "C" void kernel_launch(void* const* d_in, const int* in_sizes, int n_in,
                              void* d_out, int out_size, void* d_ws, size_t ws_size,
                              hipStream_t stream) {
  const float* inputs = (const float*)d_in[0];
  const int* mask = (const int*)d_in[1];
  const int* labels = (const int*)d_in[2];
  const float* W = (const float*)d_in[3];
  const float* bias = (const float*)d_in[4];
  const float* trans = (const float*)d_in[5];
  const float* startT = (const float*)d_in[6];
  const float* endT = (const float*)d_in[7];

  float* out = (float*)d_out;
  float* scores = out;
  float* tagsOut = out + (size_t)B_ * T_ * K_;
  float* lossSlot = out + (size_t)B_ * T_ * K_ + B_ * T_;
  float* P = (float*)d_ws;

  const size_t per = (size_t)K_ * MROWS * sizeof(float);  // 6.55 MB
  int SK;
  if (ws_size >= 4 * per) SK = 4;
  else if (ws_size >= 2 * per) SK = 2;
  else SK = 1;
  const int chunkK = D_ / SK;

  dim3 g1(MROWS / 128, SK);
  gemm_kernel<<<g1, 256, 0, stream>>>(inputs, W, P, chunkK);

  combine_kernel<<<MROWS / 128, 256, 0, stream>>>(P, SK, bias, mask, scores, lossSlot);

  dim3 g3(B_, 2);
  crf_kernel<<<g3, 256, 0, stream>>>(scores, mask, labels, trans, startT, endT,
                                     tagsOut, lossSlot);
}

// Round 4
// 663.907 us; speedup vs baseline: 5.7228x; 5.7228x over previous
//
#include <hip/hip_runtime.h>

#define B_ 64
#define T_ 512
#define D_ 1024
#define K_ 50
#define MROWS (B_ * T_)  // 32768

// ---------------------------------------------------------------------------
// Kernel 1: emissions GEMM, split-K=2. P0 -> d_out scores region (row-major
// partial), P1 -> ws (row-major partial). grid (256, 2), 256 threads.
// BM=128, per-thread 2 rows x 13 cols = 26 acc VGPRs. No min-waves clamp.
// As quad-swizzled for optimal b128 bank spread; Wt reads are broadcasts.
// ---------------------------------------------------------------------------
__global__ __launch_bounds__(256) void gemm_kernel(const float* __restrict__ A,
                                                   const float* __restrict__ W,
                                                   float* __restrict__ P0,
                                                   float* __restrict__ P1) {
  __shared__ float As[128][20];
  __shared__ float Wt[52][20];

  const int tid = threadIdx.x;
  const int rowBase = blockIdx.x * 128;
  const int kBase = blockIdx.y * 512;
  float* __restrict__ P = blockIdx.y ? P1 : P0;

  const int rg = tid & 63;
  const int cg = tid >> 6;
  const int c0 = cg * 13;
  const int swr = (rg >> 3) & 3;

  float acc[2][13];
#pragma unroll
  for (int i = 0; i < 2; i++)
#pragma unroll
    for (int j = 0; j < 13; j++) acc[i][j] = 0.f;

  const int q = tid & 3;
  const int rr = tid >> 2;

  for (int ch = 0; ch < 32; ++ch) {
    const int kb = kBase + (ch << 4);
#pragma unroll
    for (int s = 0; s < 2; s++) {
      const int r = rr + 64 * s;
      const float4 v = *(const float4*)&A[(size_t)(rowBase + r) * 1024 + kb + q * 4];
      const int p = (q + ((r >> 3) & 3)) & 3;
      *(float4*)&As[r][p * 4] = v;
    }
#pragma unroll
    for (int s = 0; s < 4; s++) {
      const int l = tid + 256 * s;
      if (l < 832) {
        const int kk = l / 52;
        const int c = l - kk * 52;
        Wt[c][kk] = (c < 50) ? W[(size_t)(kb + kk) * 50 + c] : 0.f;
      }
    }
    __syncthreads();
#pragma unroll
    for (int k4 = 0; k4 < 4; k4++) {
      const int pq = ((k4 + swr) & 3) * 4;
      const float4 a0 = *(const float4*)&As[rg][pq];
      const float4 a1 = *(const float4*)&As[rg + 64][pq];
#pragma unroll
      for (int j = 0; j < 13; j++) {
        const float4 w = *(const float4*)&Wt[c0 + j][k4 * 4];
        float t0 = acc[0][j], t1 = acc[1][j];
        t0 = fmaf(a0.x, w.x, t0); t1 = fmaf(a1.x, w.x, t1);
        t0 = fmaf(a0.y, w.y, t0); t1 = fmaf(a1.y, w.y, t1);
        t0 = fmaf(a0.z, w.z, t0); t1 = fmaf(a1.z, w.z, t1);
        t0 = fmaf(a0.w, w.w, t0); t1 = fmaf(a1.w, w.w, t1);
        acc[0][j] = t0; acc[1][j] = t1;
      }
    }
    __syncthreads();
  }
#pragma unroll
  for (int j = 0; j < 13; j++) {
    const int c = c0 + j;
    if (c < 50) {
      P[(size_t)(rowBase + rg) * 50 + c] = acc[0][j];
      P[(size_t)(rowBase + rg + 64) * 50 + c] = acc[1][j];
    }
  }
}

// ---------------------------------------------------------------------------
// Kernel 2: combine P0 (in d_out) + P1 (ws) + bias, apply mask, write scores
// in place. Per-thread same-address read/write: race-free, fully coalesced.
// ---------------------------------------------------------------------------
__global__ __launch_bounds__(256) void combine_kernel(const float* __restrict__ P1,
                                                      const float* __restrict__ bias,
                                                      const int* __restrict__ mask,
                                                      float* __restrict__ scores,
                                                      float* __restrict__ lossSlot) {
  const int idx = blockIdx.x * 256 + threadIdx.x;
  const int m = idx / 50;
  const int c = idx - m * 50;
  const float v = (scores[idx] + P1[idx] + bias[c]) * (float)mask[m];
  scores[idx] = v;
  if (idx == 0) *lossSlot = 0.f;
}

// ---------------------------------------------------------------------------
// Kernel 3: CRF. grid (64,2), 256 threads. NO address-taken private arrays:
// float4 LDS reads are consumed immediately; tables are float4[13] with
// component-static access (SROA-promotable -> registers, not scratch).
//   y==0: wave0 forward chain (no barriers), waves1-3 gold partials; loss.
//   y==1: wave0 Viterbi (value fmaxf-tree + exact reverse first-index scan);
//         then chunked parallel backtrace.
// ---------------------------------------------------------------------------
__global__ __launch_bounds__(256) void crf_kernel(const float* __restrict__ scores,
                                                  const int* __restrict__ mask,
                                                  const int* __restrict__ labels,
                                                  const float* __restrict__ trans,
                                                  const float* __restrict__ startT,
                                                  const float* __restrict__ endT,
                                                  float* __restrict__ tagsOut,
                                                  float* __restrict__ lossSlot) {
  __shared__ float x_lds[64];
  __shared__ unsigned char bp_s[511 * 52];
  __shared__ unsigned char g_s[32 * 52];
  __shared__ unsigned char chin_s[32];
  __shared__ float redp_s[4];
  __shared__ int redm_s[4];
  __shared__ float logZ_s;
  __shared__ int last_s;

  const int b = blockIdx.x;
  const int tid = threadIdx.x;
  const int wave = tid >> 6;
  const int lane = tid & 63;
  const int k = lane;
  const int kc = (k < 50) ? k : 49;
  const size_t sb = (size_t)b * T_ * 50;
  const int bT = b * T_;

  if (blockIdx.y == 0) {
    // ================= forward + gold + loss =================
    if (wave == 0) {
      float4 eTv[13];
#pragma unroll
      for (int u = 0; u < 13; u++) {
        const int j = 4 * u;
        eTv[u].x = (j + 0 < 50) ? __expf(trans[(j + 0) * 50 + kc]) : 0.f;
        eTv[u].y = (j + 1 < 50) ? __expf(trans[(j + 1) * 50 + kc]) : 0.f;
        eTv[u].z = (j + 2 < 50) ? __expf(trans[(j + 2) * 50 + kc]) : 0.f;
        eTv[u].w = (j + 3 < 50) ? __expf(trans[(j + 3) * 50 + kc]) : 0.f;
      }
      float af = (k < 50) ? (startT[k] + scores[sb + k]) : -1e30f;
      float M = __int_as_float(__builtin_amdgcn_readfirstlane(__float_as_int(af)));
      float em0 = scores[sb + 50 + kc];
      float em1 = scores[sb + 100 + kc];
      int mk0 = mask[bT + 1];
      int mk1 = mask[bT + 2];
      for (int t = 1; t < T_; ++t) {
        const float emit = em0;
        const int mt = mk0;
        em0 = em1; mk0 = mk1;
        if (t + 2 < T_) {
          em1 = scores[sb + (size_t)(t + 2) * 50 + kc];
          mk1 = mask[bT + t + 2];
        }
        const float e = __expf(af - M);
        x_lds[lane] = e;  // same-wave DS in-order; no barrier
        float p0 = 0.f, p1 = 0.f, p2 = 0.f, p3 = 0.f;
#pragma unroll
        for (int u = 0; u < 13; u++) {
          const float4 w = *(const float4*)&x_lds[4 * u];  // uniform broadcast
          p0 = fmaf(w.x, eTv[u].x, p0);
          p1 = fmaf(w.y, eTv[u].y, p1);
          p2 = fmaf(w.z, eTv[u].z, p2);
          p3 = fmaf(w.w, eTv[u].w, p3);
        }
        const float S = (p0 + p1) + (p2 + p3);
        const float afn = M + __logf(S) + emit;
        af = (mt > 0 && k < 50) ? afn : af;
        M = __int_as_float(__builtin_amdgcn_readfirstlane(__float_as_int(af)));
      }
      const float x = (k < 50) ? (af + endT[k]) : -3e38f;
      float mx = x;
#pragma unroll
      for (int off = 32; off >= 1; off >>= 1) mx = fmaxf(mx, __shfl_xor(mx, off));
      float sm = (k < 50) ? __expf(x - mx) : 0.f;
#pragma unroll
      for (int off = 32; off >= 1; off >>= 1) sm += __shfl_xor(sm, off);
      if (lane == 0) logZ_s = mx + __logf(sm);
    } else {
      float part = 0.f;
      int mcnt = 0;
#pragma unroll
      for (int s = 0; s < 3; s++) {
        const int t = (tid - 64) + 192 * s;
        if (t < T_) {
          const int lt = labels[bT + t];
          const int mt = mask[bT + t];
          mcnt += mt;
          if (mt > 0) part += scores[sb + (size_t)t * 50 + lt];
          if (t < T_ - 1) {
            const int ln = labels[bT + t + 1];
            const int mn = mask[bT + t + 1];
            if (mn > 0) part += trans[lt * 50 + ln];
          }
        }
      }
#pragma unroll
      for (int off = 32; off >= 1; off >>= 1) {
        part += __shfl_xor(part, off);
        mcnt += __shfl_xor(mcnt, off);
      }
      if (lane == 0) { redp_s[wave] = part; redm_s[wave] = mcnt; }
    }
    __syncthreads();
    if (tid == 0) {
      float gold = redp_s[1] + redp_s[2] + redp_s[3];
      const int tot = redm_s[1] + redm_s[2] + redm_s[3];
      const int l0 = labels[bT];
      const int llast = labels[bT + (tot - 1)];
      gold += startT[l0] + endT[llast];
      atomicAdd(lossSlot, -(gold - logZ_s));
    }
  } else {
    // ================= Viterbi =================
    if (wave == 0) {
      float4 Tv[13];
#pragma unroll
      for (int u = 0; u < 13; u++) {
        const int j = 4 * u;
        Tv[u].x = (j + 0 < 50) ? trans[(j + 0) * 50 + kc] : -1e30f;
        Tv[u].y = (j + 1 < 50) ? trans[(j + 1) * 50 + kc] : -1e30f;
        Tv[u].z = (j + 2 < 50) ? trans[(j + 2) * 50 + kc] : -1e30f;
        Tv[u].w = (j + 3 < 50) ? trans[(j + 3) * 50 + kc] : -1e30f;
      }
      float av = (k < 50) ? (startT[k] + scores[sb + k]) : -1e30f;
      float em0 = scores[sb + 50 + kc];
      float em1 = scores[sb + 100 + kc];
      int mk0 = mask[bT + 1];
      int mk1 = mask[bT + 2];
      for (int t = 1; t < T_; ++t) {
        const float emit = em0;
        const int mt = mk0;
        em0 = em1; mk0 = mk1;
        if (t + 2 < T_) {
          em1 = scores[sb + (size_t)(t + 2) * 50 + kc];
          mk1 = mask[bT + t + 2];
        }
        x_lds[lane] = av;
        float4 u0, u1, u2, u3, u4, u5, u6, u7, u8, u9, u10, u11, u12;
        float m13[13];
#define VIT_QUAD(Q, UQ)                                            \
        {                                                          \
          const float4 w = *(const float4*)&x_lds[4 * (Q)];        \
          UQ.x = w.x + Tv[Q].x; UQ.y = w.y + Tv[Q].y;              \
          UQ.z = w.z + Tv[Q].z; UQ.w = w.w + Tv[Q].w;              \
          m13[Q] = fmaxf(fmaxf(UQ.x, UQ.y), fmaxf(UQ.z, UQ.w));    \
        }
        VIT_QUAD(0, u0)   VIT_QUAD(1, u1)   VIT_QUAD(2, u2)
        VIT_QUAD(3, u3)   VIT_QUAD(4, u4)   VIT_QUAD(5, u5)
        VIT_QUAD(6, u6)   VIT_QUAD(7, u7)   VIT_QUAD(8, u8)
        VIT_QUAD(9, u9)   VIT_QUAD(10, u10) VIT_QUAD(11, u11)
        VIT_QUAD(12, u12)
#undef VIT_QUAD
        const float h0 = fmaxf(m13[0], m13[1]);
        const float h1 = fmaxf(m13[2], m13[3]);
        const float h2 = fmaxf(m13[4], m13[5]);
        const float h3 = fmaxf(m13[6], m13[7]);
        const float h4 = fmaxf(m13[8], m13[9]);
        const float h5 = fmaxf(m13[10], m13[11]);
        const float best = fmaxf(fmaxf(fmaxf(h0, h1), fmaxf(h2, h3)),
                                 fmaxf(fmaxf(h4, h5), m13[12]));
        // exact first-index recovery: reverse scan, lowest j wins
        int bj = 0;
#define VIT_SCAN(Q, UQ)                                   \
        bj = (UQ.w == best) ? 4 * (Q) + 3 : bj;           \
        bj = (UQ.z == best) ? 4 * (Q) + 2 : bj;           \
        bj = (UQ.y == best) ? 4 * (Q) + 1 : bj;           \
        bj = (UQ.x == best) ? 4 * (Q) + 0 : bj;
        VIT_SCAN(12, u12) VIT_SCAN(11, u11) VIT_SCAN(10, u10)
        VIT_SCAN(9, u9)   VIT_SCAN(8, u8)   VIT_SCAN(7, u7)
        VIT_SCAN(6, u6)   VIT_SCAN(5, u5)   VIT_SCAN(4, u4)
        VIT_SCAN(3, u3)   VIT_SCAN(2, u2)   VIT_SCAN(1, u1)
        VIT_SCAN(0, u0)
#undef VIT_SCAN
        if (k < 50) bp_s[(t - 1) * 52 + k] = (unsigned char)((mt > 0) ? bj : k);
        av = (mt > 0 && k < 50) ? (best + emit) : av;
      }
      float x = (k < 50) ? (av + endT[k]) : -3e38f;
      int xi = (k < 50) ? k : 63;
#pragma unroll
      for (int off = 32; off >= 1; off >>= 1) {
        const float ov = __shfl_xor(x, off);
        const int oi = __shfl_xor(xi, off);
        if (ov > x || (ov == x && oi < xi)) { x = ov; xi = oi; }
      }
      if (lane == 0) last_s = xi;
    }
    __syncthreads();
    const int last = last_s;
    // phase A: compose 16-step chunk maps
    for (int p = 0; p < 7; p++) {
      const int idx = tid + 256 * p;
      if (idx < 1600) {
        const int c = idx / 50;
        const int s2 = idx - c * 50;
        int x2 = s2;
        const int lo = 16 * c;
        const int hi = min(16 * c + 15, 510);
        for (int i = hi; i >= lo; --i) x2 = bp_s[i * 52 + x2];
        g_s[c * 52 + s2] = (unsigned char)x2;
      }
    }
    __syncthreads();
    // phase B: serial chunk-boundary walk
    if (tid == 0) {
      int cur = last;
      chin_s[31] = (unsigned char)cur;
      for (int c = 31; c >= 1; --c) {
        cur = g_s[c * 52 + cur];
        chin_s[c - 1] = (unsigned char)cur;
      }
      const int m511 = mask[bT + 511];
      tagsOut[(size_t)bT + 511] = (float)((m511 > 0) ? last : 0);
    }
    __syncthreads();
    // phase C: per-chunk backtrace + tag stores
    if (tid < 32) {
      const int c = tid;
      int x3 = chin_s[c];
      const int lo = 16 * c;
      const int hi = min(16 * c + 15, 510);
      for (int i = hi; i >= lo; --i) {
        x3 = bp_s[i * 52 + x3];
        const int mi = mask[bT + i];
        tagsOut[(size_t)bT + i] = (float)((mi > 0) ? x3 : 0);
      }
    }
  }
}

// ---------------------------------------------------------------------------
extern "C" void kernel_launch(void* const* d_in, const int* in_sizes, int n_in,
                              void* d_out, int out_size, void* d_ws, size_t ws_size,
                              hipStream_t stream) {
  const float* inputs = (const float*)d_in[0];
  const int* mask = (const int*)d_in[1];
  const int* labels = (const int*)d_in[2];
  const float* W = (const float*)d_in[3];
  const float* bias = (const float*)d_in[4];
  const float* trans = (const float*)d_in[5];
  const float* startT = (const float*)d_in[6];
  const float* endT = (const float*)d_in[7];

  float* out = (float*)d_out;
  float* scores = out;
  float* tagsOut = out + (size_t)B_ * T_ * K_;
  float* lossSlot = out + (size_t)B_ * T_ * K_ + B_ * T_;
  float* P1 = (float*)d_ws;  // 6.55 MB (proven to fit in R1)

  dim3 g1(MROWS / 128, 2);
  gemm_kernel<<<g1, 256, 0, stream>>>(inputs, W, scores, P1);

  combine_kernel<<<(K_ * MROWS) / 256, 256, 0, stream>>>(P1, bias, mask, scores,
                                                         lossSlot);

  dim3 g3(B_, 2);
  crf_kernel<<<g3, 256, 0, stream>>>(scores, mask, labels, trans, startT, endT,
                                     tagsOut, lossSlot);
}

// Round 5
// 610.433 us; speedup vs baseline: 6.2241x; 1.0876x over previous
//
#include <hip/hip_runtime.h>

#define B_ 64
#define T_ 512
#define D_ 1024
#define K_ 50
#define MROWS (B_ * T_)  // 32768

// ---------------------------------------------------------------------------
// Kernel 1: emissions GEMM, split-K=2. P0 -> d_out scores region, P1 -> ws.
// grid (256, 2), 256 threads. BM=128, per-thread 4 rows x 7 cols = 28 acc.
// LDS-read:FMA issue ratio 0.59 (vs 0.87 at 2x13). Register-prefetch
// double-buffer: next tile's global loads issue before compute.
// As quad-swizzled (conflict-free b128); Wt reads are 2-address broadcasts.
// ---------------------------------------------------------------------------
__global__ __launch_bounds__(256) void gemm_kernel(const float* __restrict__ A,
                                                   const float* __restrict__ W,
                                                   float* __restrict__ P0,
                                                   float* __restrict__ P1) {
  __shared__ float As[128][20];
  __shared__ float Wt[52][20];

  const int tid = threadIdx.x;
  const int rowBase = blockIdx.x * 128;
  const int kBase = blockIdx.y * 512;
  float* __restrict__ P = blockIdx.y ? P1 : P0;

  const int rg = tid & 31;   // row lane: rows rg + 32*i
  const int cg = tid >> 5;   // col group 0..7, 7 cols each
  const int c0 = cg * 7;
  const int swr = (rg >> 3) & 3;

  // staging indices (constant across tiles)
  const int q = tid & 3;
  const int rr = tid >> 2;
  const int pA0 = ((q + ((rr >> 3) & 3)) & 3) * 4;
  const int pA1 = ((q + (((rr + 64) >> 3) & 3)) & 3) * 4;
  const int kk0 = tid / 52,         cw0 = tid - kk0 * 52;
  const int kk1 = (tid + 256) / 52, cw1 = tid + 256 - kk1 * 52;
  const int kk2 = (tid + 512) / 52, cw2 = tid + 512 - kk2 * 52;
  const int kk3 = (tid + 768) / 52, cw3 = tid + 768 - kk3 * 52;  // tid<64 only

  float acc[4][7];
#pragma unroll
  for (int i = 0; i < 4; i++)
#pragma unroll
    for (int j = 0; j < 7; j++) acc[i][j] = 0.f;

  const float* __restrict__ pA0g = &A[(size_t)(rowBase + rr) * 1024 + kBase + q * 4];
  const float* __restrict__ pA1g = &A[(size_t)(rowBase + rr + 64) * 1024 + kBase + q * 4];
  const float* __restrict__ pWg = &W[(size_t)kBase * 50];

  // prologue: load tile 0 into regs
  float4 nA0 = *(const float4*)pA0g;
  float4 nA1 = *(const float4*)pA1g;
  float nW0 = (cw0 < 50) ? pWg[(size_t)kk0 * 50 + cw0] : 0.f;
  float nW1 = (cw1 < 50) ? pWg[(size_t)kk1 * 50 + cw1] : 0.f;
  float nW2 = (cw2 < 50) ? pWg[(size_t)kk2 * 50 + cw2] : 0.f;
  float nW3 = (tid < 64 && cw3 < 50) ? pWg[(size_t)kk3 * 50 + cw3] : 0.f;

  for (int ch = 0; ch < 32; ++ch) {
    // write staged regs -> LDS
    *(float4*)&As[rr][pA0] = nA0;
    *(float4*)&As[rr + 64][pA1] = nA1;
    Wt[cw0][kk0] = nW0;
    Wt[cw1][kk1] = nW1;
    Wt[cw2][kk2] = nW2;
    if (tid < 64) Wt[cw3][kk3] = nW3;
    __syncthreads();
    // issue next tile's loads (latency hides under compute)
    if (ch < 31) {
      const int off = (ch + 1) * 16;
      nA0 = *(const float4*)(pA0g + off);
      nA1 = *(const float4*)(pA1g + off);
      const float* pw = pWg + (size_t)off * 50;
      nW0 = (cw0 < 50) ? pw[(size_t)kk0 * 50 + cw0] : 0.f;
      nW1 = (cw1 < 50) ? pw[(size_t)kk1 * 50 + cw1] : 0.f;
      nW2 = (cw2 < 50) ? pw[(size_t)kk2 * 50 + cw2] : 0.f;
      nW3 = (tid < 64 && cw3 < 50) ? pw[(size_t)kk3 * 50 + cw3] : 0.f;
    }
#pragma unroll
    for (int k4 = 0; k4 < 4; k4++) {
      const int pq = ((k4 + swr) & 3) * 4;
      const float4 a0 = *(const float4*)&As[rg][pq];
      const float4 a1 = *(const float4*)&As[rg + 32][pq];
      const float4 a2 = *(const float4*)&As[rg + 64][pq];
      const float4 a3 = *(const float4*)&As[rg + 96][pq];
#pragma unroll
      for (int j = 0; j < 7; j++) {
        const float4 w = *(const float4*)&Wt[c0 + j][k4 * 4];
        float t0 = acc[0][j], t1 = acc[1][j], t2 = acc[2][j], t3 = acc[3][j];
        t0 = fmaf(a0.x, w.x, t0); t1 = fmaf(a1.x, w.x, t1);
        t2 = fmaf(a2.x, w.x, t2); t3 = fmaf(a3.x, w.x, t3);
        t0 = fmaf(a0.y, w.y, t0); t1 = fmaf(a1.y, w.y, t1);
        t2 = fmaf(a2.y, w.y, t2); t3 = fmaf(a3.y, w.y, t3);
        t0 = fmaf(a0.z, w.z, t0); t1 = fmaf(a1.z, w.z, t1);
        t2 = fmaf(a2.z, w.z, t2); t3 = fmaf(a3.z, w.z, t3);
        t0 = fmaf(a0.w, w.w, t0); t1 = fmaf(a1.w, w.w, t1);
        t2 = fmaf(a2.w, w.w, t2); t3 = fmaf(a3.w, w.w, t3);
        acc[0][j] = t0; acc[1][j] = t1; acc[2][j] = t2; acc[3][j] = t3;
      }
    }
    __syncthreads();
  }
#pragma unroll
  for (int j = 0; j < 7; j++) {
    const int c = c0 + j;
    if (c < 50) {
#pragma unroll
      for (int i = 0; i < 4; i++)
        P[(size_t)(rowBase + rg + 32 * i) * 50 + c] = acc[i][j];
    }
  }
}

// ---------------------------------------------------------------------------
// Kernel 2: combine P0 (in d_out) + P1 (ws) + bias, apply mask, in place.
// ---------------------------------------------------------------------------
__global__ __launch_bounds__(256) void combine_kernel(const float* __restrict__ P1,
                                                      const float* __restrict__ bias,
                                                      const int* __restrict__ mask,
                                                      float* __restrict__ scores,
                                                      float* __restrict__ lossSlot) {
  const int idx = blockIdx.x * 256 + threadIdx.x;
  const int m = idx / 50;
  const int c = idx - m * 50;
  const float v = (scores[idx] + P1[idx] + bias[c]) * (float)mask[m];
  scores[idx] = v;
  if (idx == 0) *lossSlot = 0.f;
}

// Pin a float4-table element set in VGPRs: compiler cannot rematerialize
// (re-load from global) past this barrier.
#define PIN4(V) asm volatile("" : "+v"(V.x), "+v"(V.y), "+v"(V.z), "+v"(V.w))

// ---------------------------------------------------------------------------
// Kernel 3: CRF. grid (64, 3), 64 threads (ONE wave), launch_bounds(64,1)
// -> full 512-VGPR budget so the 52-entry transition tables stay register-
// resident (R4's VGPR=60 remat disaster).
//   y==0: forward (log-partition) chain, atomicAdd(+logZ)
//   y==1: Viterbi + chunked backtrace
//   y==2: gold score, atomicAdd(-gold)
// ---------------------------------------------------------------------------
__global__ __launch_bounds__(64, 1) void crf_kernel(const float* __restrict__ scores,
                                                    const int* __restrict__ mask,
                                                    const int* __restrict__ labels,
                                                    const float* __restrict__ trans,
                                                    const float* __restrict__ startT,
                                                    const float* __restrict__ endT,
                                                    float* __restrict__ tagsOut,
                                                    float* __restrict__ lossSlot) {
  __shared__ float x_lds[64];
  __shared__ unsigned char bp_s[511 * 52];
  __shared__ unsigned char g_s[32 * 52];
  __shared__ unsigned char chin_s[32];

  const int b = blockIdx.x;
  const int lane = threadIdx.x;
  const int k = lane;
  const int kc = (k < 50) ? k : 49;
  const size_t sb = (size_t)b * T_ * 50;
  const int bT = b * T_;

  if (blockIdx.y == 0) {
    // ================= forward (log-partition) =================
    float4 eTv[13];
#pragma unroll
    for (int u = 0; u < 13; u++) {
      const int j = 4 * u;
      eTv[u].x = (j + 0 < 50) ? __expf(trans[(j + 0) * 50 + kc]) : 0.f;
      eTv[u].y = (j + 1 < 50) ? __expf(trans[(j + 1) * 50 + kc]) : 0.f;
      eTv[u].z = (j + 2 < 50) ? __expf(trans[(j + 2) * 50 + kc]) : 0.f;
      eTv[u].w = (j + 3 < 50) ? __expf(trans[(j + 3) * 50 + kc]) : 0.f;
      PIN4(eTv[u]);
    }
    float af = (k < 50) ? (startT[k] + scores[sb + k]) : -1e30f;
    float M = __int_as_float(__builtin_amdgcn_readfirstlane(__float_as_int(af)));
    float em0 = scores[sb + 50 + kc];
    float em1 = scores[sb + 100 + kc];
    int mk0 = mask[bT + 1];
    int mk1 = mask[bT + 2];
    for (int t = 1; t < T_; ++t) {
      const float emit = em0;
      const int mt = mk0;
      em0 = em1; mk0 = mk1;
      if (t + 2 < T_) {
        em1 = scores[sb + (size_t)(t + 2) * 50 + kc];
        mk1 = mask[bT + t + 2];
      }
      const float e = __expf(af - M);
      x_lds[lane] = e;  // same-wave DS in-order; no barrier
      float p0 = 0.f, p1 = 0.f, p2 = 0.f, p3 = 0.f;
#pragma unroll
      for (int u = 0; u < 13; u++) {
        const float4 w = *(const float4*)&x_lds[4 * u];  // uniform broadcast
        p0 = fmaf(w.x, eTv[u].x, p0);
        p1 = fmaf(w.y, eTv[u].y, p1);
        p2 = fmaf(w.z, eTv[u].z, p2);
        p3 = fmaf(w.w, eTv[u].w, p3);
      }
      const float S = (p0 + p1) + (p2 + p3);
      const float afn = M + __logf(S) + emit;
      af = (mt > 0 && k < 50) ? afn : af;
      M = __int_as_float(__builtin_amdgcn_readfirstlane(__float_as_int(af)));
    }
    const float x = (k < 50) ? (af + endT[k]) : -3e38f;
    float mx = x;
#pragma unroll
    for (int off = 32; off >= 1; off >>= 1) mx = fmaxf(mx, __shfl_xor(mx, off));
    float sm = (k < 50) ? __expf(x - mx) : 0.f;
#pragma unroll
    for (int off = 32; off >= 1; off >>= 1) sm += __shfl_xor(sm, off);
    if (lane == 0) atomicAdd(lossSlot, mx + __logf(sm));  // +logZ
  } else if (blockIdx.y == 1) {
    // ================= Viterbi =================
    float4 Tv[13];
#pragma unroll
    for (int u = 0; u < 13; u++) {
      const int j = 4 * u;
      Tv[u].x = (j + 0 < 50) ? trans[(j + 0) * 50 + kc] : -1e30f;
      Tv[u].y = (j + 1 < 50) ? trans[(j + 1) * 50 + kc] : -1e30f;
      Tv[u].z = (j + 2 < 50) ? trans[(j + 2) * 50 + kc] : -1e30f;
      Tv[u].w = (j + 3 < 50) ? trans[(j + 3) * 50 + kc] : -1e30f;
      PIN4(Tv[u]);
    }
    float av = (k < 50) ? (startT[k] + scores[sb + k]) : -1e30f;
    float em0 = scores[sb + 50 + kc];
    float em1 = scores[sb + 100 + kc];
    int mk0 = mask[bT + 1];
    int mk1 = mask[bT + 2];
    for (int t = 1; t < T_; ++t) {
      const float emit = em0;
      const int mt = mk0;
      em0 = em1; mk0 = mk1;
      if (t + 2 < T_) {
        em1 = scores[sb + (size_t)(t + 2) * 50 + kc];
        mk1 = mask[bT + t + 2];
      }
      x_lds[lane] = av;
      float4 u0, u1, u2, u3, u4, u5, u6, u7, u8, u9, u10, u11, u12;
      float m13[13];
#define VIT_QUAD(Q, UQ)                                            \
      {                                                            \
        const float4 w = *(const float4*)&x_lds[4 * (Q)];          \
        UQ.x = w.x + Tv[Q].x; UQ.y = w.y + Tv[Q].y;                \
        UQ.z = w.z + Tv[Q].z; UQ.w = w.w + Tv[Q].w;                \
        m13[Q] = fmaxf(fmaxf(UQ.x, UQ.y), fmaxf(UQ.z, UQ.w));      \
      }
      VIT_QUAD(0, u0)   VIT_QUAD(1, u1)   VIT_QUAD(2, u2)
      VIT_QUAD(3, u3)   VIT_QUAD(4, u4)   VIT_QUAD(5, u5)
      VIT_QUAD(6, u6)   VIT_QUAD(7, u7)   VIT_QUAD(8, u8)
      VIT_QUAD(9, u9)   VIT_QUAD(10, u10) VIT_QUAD(11, u11)
      VIT_QUAD(12, u12)
#undef VIT_QUAD
      const float h0 = fmaxf(m13[0], m13[1]);
      const float h1 = fmaxf(m13[2], m13[3]);
      const float h2 = fmaxf(m13[4], m13[5]);
      const float h3 = fmaxf(m13[6], m13[7]);
      const float h4 = fmaxf(m13[8], m13[9]);
      const float h5 = fmaxf(m13[10], m13[11]);
      const float best = fmaxf(fmaxf(fmaxf(h0, h1), fmaxf(h2, h3)),
                               fmaxf(fmaxf(h4, h5), m13[12]));
      int bj = 0;  // exact first-index recovery (reverse scan, lowest j wins)
#define VIT_SCAN(Q, UQ)                                   \
      bj = (UQ.w == best) ? 4 * (Q) + 3 : bj;             \
      bj = (UQ.z == best) ? 4 * (Q) + 2 : bj;             \
      bj = (UQ.y == best) ? 4 * (Q) + 1 : bj;             \
      bj = (UQ.x == best) ? 4 * (Q) + 0 : bj;
      VIT_SCAN(12, u12) VIT_SCAN(11, u11) VIT_SCAN(10, u10)
      VIT_SCAN(9, u9)   VIT_SCAN(8, u8)   VIT_SCAN(7, u7)
      VIT_SCAN(6, u6)   VIT_SCAN(5, u5)   VIT_SCAN(4, u4)
      VIT_SCAN(3, u3)   VIT_SCAN(2, u2)   VIT_SCAN(1, u1)
      VIT_SCAN(0, u0)
#undef VIT_SCAN
      if (k < 50) bp_s[(t - 1) * 52 + k] = (unsigned char)((mt > 0) ? bj : k);
      av = (mt > 0 && k < 50) ? (best + emit) : av;
    }
    float x = (k < 50) ? (av + endT[k]) : -3e38f;
    int xi = (k < 50) ? k : 63;
#pragma unroll
    for (int off = 32; off >= 1; off >>= 1) {
      const float ov = __shfl_xor(x, off);
      const int oi = __shfl_xor(xi, off);
      if (ov > x || (ov == x && oi < xi)) { x = ov; xi = oi; }
    }
    const int last = xi;  // butterfly converges: all lanes hold argmax
    __syncthreads();
    // phase A: compose 16-step chunk maps (1600 = 64 lanes x 25)
#pragma unroll 1
    for (int p = 0; p < 25; p++) {
      const int idx = lane + 64 * p;
      const int c = idx / 50;
      const int s2 = idx - c * 50;
      int x2 = s2;
      const int lo = 16 * c;
      const int hi = min(16 * c + 15, 510);
      for (int i = hi; i >= lo; --i) x2 = bp_s[i * 52 + x2];
      g_s[c * 52 + s2] = (unsigned char)x2;
    }
    __syncthreads();
    // phase B: serial chunk-boundary walk
    if (lane == 0) {
      int cur = last;
      chin_s[31] = (unsigned char)cur;
      for (int c = 31; c >= 1; --c) {
        cur = g_s[c * 52 + cur];
        chin_s[c - 1] = (unsigned char)cur;
      }
      const int m511 = mask[bT + 511];
      tagsOut[(size_t)bT + 511] = (float)((m511 > 0) ? last : 0);
    }
    __syncthreads();
    // phase C: per-chunk backtrace + tag stores
    if (lane < 32) {
      const int c = lane;
      int x3 = chin_s[c];
      const int lo = 16 * c;
      const int hi = min(16 * c + 15, 510);
      for (int i = hi; i >= lo; --i) {
        x3 = bp_s[i * 52 + x3];
        const int mi = mask[bT + i];
        tagsOut[(size_t)bT + i] = (float)((mi > 0) ? x3 : 0);
      }
    }
  } else {
    // ================= gold score =================
    float part = 0.f;
    int mcnt = 0;
#pragma unroll
    for (int s = 0; s < 8; s++) {
      const int t = lane + 64 * s;
      const int lt = labels[bT + t];
      const int mt = mask[bT + t];
      mcnt += mt;
      if (mt > 0) part += scores[sb + (size_t)t * 50 + lt];
      if (t < T_ - 1) {
        const int ln = labels[bT + t + 1];
        const int mn = mask[bT + t + 1];
        if (mn > 0) part += trans[lt * 50 + ln];
      }
    }
#pragma unroll
    for (int off = 32; off >= 1; off >>= 1) {
      part += __shfl_xor(part, off);
      mcnt += __shfl_xor(mcnt, off);
    }
    if (lane == 0) {
      const int l0 = labels[bT];
      const int llast = labels[bT + (mcnt - 1)];
      const float gold = part + startT[l0] + endT[llast];
      atomicAdd(lossSlot, -gold);
    }
  }
}

// ---------------------------------------------------------------------------
extern "C" void kernel_launch(void* const* d_in, const int* in_sizes, int n_in,
                              void* d_out, int out_size, void* d_ws, size_t ws_size,
                              hipStream_t stream) {
  const float* inputs = (const float*)d_in[0];
  const int* mask = (const int*)d_in[1];
  const int* labels = (const int*)d_in[2];
  const float* W = (const float*)d_in[3];
  const float* bias = (const float*)d_in[4];
  const float* trans = (const float*)d_in[5];
  const float* startT = (const float*)d_in[6];
  const float* endT = (const float*)d_in[7];

  float* out = (float*)d_out;
  float* scores = out;
  float* tagsOut = out + (size_t)B_ * T_ * K_;
  float* lossSlot = out + (size_t)B_ * T_ * K_ + B_ * T_;
  float* P1 = (float*)d_ws;  // 6.55 MB (fits; proven R1)

  dim3 g1(MROWS / 128, 2);
  gemm_kernel<<<g1, 256, 0, stream>>>(inputs, W, scores, P1);

  combine_kernel<<<(K_ * MROWS) / 256, 256, 0, stream>>>(P1, bias, mask, scores,
                                                         lossSlot);

  dim3 g3(B_, 3);
  crf_kernel<<<g3, 64, 0, stream>>>(scores, mask, labels, trans, startT, endT,
                                    tagsOut, lossSlot);
}

// Round 8
// 580.821 us; speedup vs baseline: 6.5415x; 1.0510x over previous
//
#include <hip/hip_runtime.h>

#define B_ 64
#define T_ 512
#define D_ 1024
#define K_ 50
#define MROWS (B_ * T_)  // 32768

// ---------------------------------------------------------------------------
// Kernel 1: emissions GEMM, runtime split-K (SK=4 if ws fits 3 partials,
// else SK=2). P(y=0) -> d_out scores region, P(y>0) -> ws partial y-1.
// grid (256, SK), 256 threads, BM=128, per-thread 4 rows x 7 cols.
// SK=4 -> 1024 blocks = 4 blocks/CU = 4 waves/SIMD (occupancy fix).
// ---------------------------------------------------------------------------
__global__ __launch_bounds__(256) void gemm_kernel(const float* __restrict__ A,
                                                   const float* __restrict__ W,
                                                   float* __restrict__ P0,
                                                   float* __restrict__ Pws,
                                                   int chunkK) {
  __shared__ float As[128][20];
  __shared__ float Wt[52][20];

  const int tid = threadIdx.x;
  const int rowBase = blockIdx.x * 128;
  const int kBase = blockIdx.y * chunkK;
  float* __restrict__ P =
      (blockIdx.y == 0) ? P0 : (Pws + (size_t)(blockIdx.y - 1) * K_ * MROWS);

  const int rg = tid & 31;
  const int cg = tid >> 5;
  const int c0 = cg * 7;
  const int swr = (rg >> 3) & 3;

  const int q = tid & 3;
  const int rr = tid >> 2;
  const int pA0 = ((q + ((rr >> 3) & 3)) & 3) * 4;
  const int pA1 = ((q + (((rr + 64) >> 3) & 3)) & 3) * 4;
  const int kk0 = tid / 52,         cw0 = tid - kk0 * 52;
  const int kk1 = (tid + 256) / 52, cw1 = tid + 256 - kk1 * 52;
  const int kk2 = (tid + 512) / 52, cw2 = tid + 512 - kk2 * 52;
  const int kk3 = (tid + 768) / 52, cw3 = tid + 768 - kk3 * 52;

  float acc[4][7];
#pragma unroll
  for (int i = 0; i < 4; i++)
#pragma unroll
    for (int j = 0; j < 7; j++) acc[i][j] = 0.f;

  const float* __restrict__ pA0g = &A[(size_t)(rowBase + rr) * 1024 + kBase + q * 4];
  const float* __restrict__ pA1g = &A[(size_t)(rowBase + rr + 64) * 1024 + kBase + q * 4];
  const float* __restrict__ pWg = &W[(size_t)kBase * 50];

  float4 nA0 = *(const float4*)pA0g;
  float4 nA1 = *(const float4*)pA1g;
  float nW0 = (cw0 < 50) ? pWg[(size_t)kk0 * 50 + cw0] : 0.f;
  float nW1 = (cw1 < 50) ? pWg[(size_t)kk1 * 50 + cw1] : 0.f;
  float nW2 = (cw2 < 50) ? pWg[(size_t)kk2 * 50 + cw2] : 0.f;
  float nW3 = (tid < 64 && cw3 < 50) ? pWg[(size_t)kk3 * 50 + cw3] : 0.f;

  const int iters = chunkK >> 4;
  for (int ch = 0; ch < iters; ++ch) {
    *(float4*)&As[rr][pA0] = nA0;
    *(float4*)&As[rr + 64][pA1] = nA1;
    Wt[cw0][kk0] = nW0;
    Wt[cw1][kk1] = nW1;
    Wt[cw2][kk2] = nW2;
    if (tid < 64) Wt[cw3][kk3] = nW3;
    __syncthreads();
    if (ch < iters - 1) {
      const int off = (ch + 1) * 16;
      nA0 = *(const float4*)(pA0g + off);
      nA1 = *(const float4*)(pA1g + off);
      const float* pw = pWg + (size_t)off * 50;
      nW0 = (cw0 < 50) ? pw[(size_t)kk0 * 50 + cw0] : 0.f;
      nW1 = (cw1 < 50) ? pw[(size_t)kk1 * 50 + cw1] : 0.f;
      nW2 = (cw2 < 50) ? pw[(size_t)kk2 * 50 + cw2] : 0.f;
      nW3 = (tid < 64 && cw3 < 50) ? pw[(size_t)kk3 * 50 + cw3] : 0.f;
    }
#pragma unroll
    for (int k4 = 0; k4 < 4; k4++) {
      const int pq = ((k4 + swr) & 3) * 4;
      const float4 a0 = *(const float4*)&As[rg][pq];
      const float4 a1 = *(const float4*)&As[rg + 32][pq];
      const float4 a2 = *(const float4*)&As[rg + 64][pq];
      const float4 a3 = *(const float4*)&As[rg + 96][pq];
#pragma unroll
      for (int j = 0; j < 7; j++) {
        const float4 w = *(const float4*)&Wt[c0 + j][k4 * 4];
        float t0 = acc[0][j], t1 = acc[1][j], t2 = acc[2][j], t3 = acc[3][j];
        t0 = fmaf(a0.x, w.x, t0); t1 = fmaf(a1.x, w.x, t1);
        t2 = fmaf(a2.x, w.x, t2); t3 = fmaf(a3.x, w.x, t3);
        t0 = fmaf(a0.y, w.y, t0); t1 = fmaf(a1.y, w.y, t1);
        t2 = fmaf(a2.y, w.y, t2); t3 = fmaf(a3.y, w.y, t3);
        t0 = fmaf(a0.z, w.z, t0); t1 = fmaf(a1.z, w.z, t1);
        t2 = fmaf(a2.z, w.z, t2); t3 = fmaf(a3.z, w.z, t3);
        t0 = fmaf(a0.w, w.w, t0); t1 = fmaf(a1.w, w.w, t1);
        t2 = fmaf(a2.w, w.w, t2); t3 = fmaf(a3.w, w.w, t3);
        acc[0][j] = t0; acc[1][j] = t1; acc[2][j] = t2; acc[3][j] = t3;
      }
    }
    __syncthreads();
  }
#pragma unroll
  for (int j = 0; j < 7; j++) {
    const int c = c0 + j;
    if (c < 50) {
#pragma unroll
      for (int i = 0; i < 4; i++)
        P[(size_t)(rowBase + rg + 32 * i) * 50 + c] = acc[i][j];
    }
  }
}

// ---------------------------------------------------------------------------
// Kernel 2: combine P0 (in d_out) + (SK-1) ws partials + bias, mask, in place.
// ---------------------------------------------------------------------------
__global__ __launch_bounds__(256) void combine_kernel(const float* __restrict__ Pws,
                                                      int nPart,
                                                      const float* __restrict__ bias,
                                                      const int* __restrict__ mask,
                                                      float* __restrict__ scores,
                                                      float* __restrict__ lossSlot) {
  const int idx = blockIdx.x * 256 + threadIdx.x;
  const int m = idx / 50;
  const int c = idx - m * 50;
  float s = scores[idx];
  for (int p = 0; p < nPart; ++p) s += Pws[(size_t)p * K_ * MROWS + idx];
  s = (s + bias[c]) * (float)mask[m];
  scores[idx] = s;
  if (idx == 0) *lossSlot = 0.f;
}

#define PIN4(V) asm volatile("" : "+v"(V.x), "+v"(V.y), "+v"(V.z), "+v"(V.w))
// float broadcast from lane J (compile-time const) — VALU only, no LDS.
#define RL(v, J) __int_as_float(__builtin_amdgcn_readlane(__float_as_int(v), (J)))

// ---------------------------------------------------------------------------
// Kernel 3: CRF. grid (64,3), 64 threads, launch_bounds(64,1).
// y==0 forward, y==1 Viterbi+backtrace, y==2 gold.
// NO LDS round-trip in the recurrence (readlane broadcasts), NO per-step
// mask load (ballot bitmasks in SGPRs, 8-phase static selection), emissions
// prefetched distance-2, Viterbi backpointer via parallel eq-mask + ctz.
// ---------------------------------------------------------------------------
__global__ __launch_bounds__(64, 1) void crf_kernel(const float* __restrict__ scores,
                                                    const int* __restrict__ mask,
                                                    const int* __restrict__ labels,
                                                    const float* __restrict__ trans,
                                                    const float* __restrict__ startT,
                                                    const float* __restrict__ endT,
                                                    float* __restrict__ tagsOut,
                                                    float* __restrict__ lossSlot) {
  __shared__ unsigned char bp_s[511 * 52];
  __shared__ unsigned char g_s[32 * 52];
  __shared__ unsigned char chin_s[32];

  const int b = blockIdx.x;
  const int lane = threadIdx.x;
  const int k = lane;
  const int kc = (k < 50) ? k : 49;
  const size_t sb = (size_t)b * T_ * 50;
  const int bT = b * T_;

  // mask bitmasks: bit tt of bmP = mask[bT + P*64 + tt] > 0
  const unsigned long long bm0 = __ballot(mask[bT + 0 * 64 + lane] > 0);
  const unsigned long long bm1 = __ballot(mask[bT + 1 * 64 + lane] > 0);
  const unsigned long long bm2 = __ballot(mask[bT + 2 * 64 + lane] > 0);
  const unsigned long long bm3 = __ballot(mask[bT + 3 * 64 + lane] > 0);
  const unsigned long long bm4 = __ballot(mask[bT + 4 * 64 + lane] > 0);
  const unsigned long long bm5 = __ballot(mask[bT + 5 * 64 + lane] > 0);
  const unsigned long long bm6 = __ballot(mask[bT + 6 * 64 + lane] > 0);
  const unsigned long long bm7 = __ballot(mask[bT + 7 * 64 + lane] > 0);

  if (blockIdx.y == 0) {
    // ================= forward (log-partition) =================
    float4 eTv[13];
#pragma unroll
    for (int u = 0; u < 13; u++) {
      const int j = 4 * u;
      eTv[u].x = (j + 0 < 50) ? __expf(trans[(j + 0) * 50 + kc]) : 0.f;
      eTv[u].y = (j + 1 < 50) ? __expf(trans[(j + 1) * 50 + kc]) : 0.f;
      eTv[u].z = (j + 2 < 50) ? __expf(trans[(j + 2) * 50 + kc]) : 0.f;
      eTv[u].w = (j + 3 < 50) ? __expf(trans[(j + 3) * 50 + kc]) : 0.f;
      PIN4(eTv[u]);
    }
    float af = (k < 50) ? (startT[k] + scores[sb + k]) : -1e30f;
    float M = __int_as_float(__builtin_amdgcn_readfirstlane(__float_as_int(af)));
    float em0 = scores[sb + 50 + kc];
    float em1 = scores[sb + 100 + kc];

#define FWD_Q(U)                                        \
    p0 = fmaf(RL(e, 4 * (U) + 0), eTv[U].x, p0);        \
    p1 = fmaf(RL(e, 4 * (U) + 1), eTv[U].y, p1);        \
    p2 = fmaf(RL(e, 4 * (U) + 2), eTv[U].z, p2);        \
    p3 = fmaf(RL(e, 4 * (U) + 3), eTv[U].w, p3);

#define FWD_BODY(T, BMV)                                             \
    {                                                                \
      const int t = (T);                                             \
      const float emit = em0;                                        \
      em0 = em1;                                                     \
      if (t + 2 < T_) em1 = scores[sb + (size_t)(t + 2) * 50 + kc];  \
      const int mt = (int)(((BMV) >> (t & 63)) & 1ull);              \
      const float e = __expf(af - M);                                \
      float p0 = 0.f, p1 = 0.f, p2 = 0.f, p3 = 0.f;                  \
      FWD_Q(0) FWD_Q(1) FWD_Q(2) FWD_Q(3) FWD_Q(4) FWD_Q(5)          \
      FWD_Q(6) FWD_Q(7) FWD_Q(8) FWD_Q(9) FWD_Q(10) FWD_Q(11)        \
      FWD_Q(12)                                                      \
      const float S = (p0 + p1) + (p2 + p3);                         \
      const float afn = M + __logf(S) + emit;                        \
      af = (mt && k < 50) ? afn : af;                                \
      M = __int_as_float(__builtin_amdgcn_readfirstlane(__float_as_int(af))); \
    }

#define FWD_PHASE(P, BMV, T0)                       \
    _Pragma("unroll 1")                             \
    for (int tt = (T0); tt < 64; ++tt) {            \
      FWD_BODY((P) * 64 + tt, BMV)                  \
    }

    FWD_PHASE(0, bm0, 1)
    FWD_PHASE(1, bm1, 0)
    FWD_PHASE(2, bm2, 0)
    FWD_PHASE(3, bm3, 0)
    FWD_PHASE(4, bm4, 0)
    FWD_PHASE(5, bm5, 0)
    FWD_PHASE(6, bm6, 0)
    FWD_PHASE(7, bm7, 0)

    const float x = (k < 50) ? (af + endT[k]) : -3e38f;
    float mx = x;
#pragma unroll
    for (int off = 32; off >= 1; off >>= 1) mx = fmaxf(mx, __shfl_xor(mx, off));
    float sm = (k < 50) ? __expf(x - mx) : 0.f;
#pragma unroll
    for (int off = 32; off >= 1; off >>= 1) sm += __shfl_xor(sm, off);
    if (lane == 0) atomicAdd(lossSlot, mx + __logf(sm));  // +logZ
  } else if (blockIdx.y == 1) {
    // ================= Viterbi =================
    float4 Tv[13];
#pragma unroll
    for (int u = 0; u < 13; u++) {
      const int j = 4 * u;
      Tv[u].x = (j + 0 < 50) ? trans[(j + 0) * 50 + kc] : -1e30f;
      Tv[u].y = (j + 1 < 50) ? trans[(j + 1) * 50 + kc] : -1e30f;
      Tv[u].z = (j + 2 < 50) ? trans[(j + 2) * 50 + kc] : -1e30f;
      Tv[u].w = (j + 3 < 50) ? trans[(j + 3) * 50 + kc] : -1e30f;
      PIN4(Tv[u]);
    }
    float av = (k < 50) ? (startT[k] + scores[sb + k]) : -1e30f;
    float em0 = scores[sb + 50 + kc];
    float em1 = scores[sb + 100 + kc];

#define VIT_Q(U, UQ, MQ)                                          \
    float4 UQ; float MQ;                                          \
    UQ.x = RL(av, 4 * (U) + 0) + Tv[U].x;                         \
    UQ.y = RL(av, 4 * (U) + 1) + Tv[U].y;                         \
    UQ.z = RL(av, 4 * (U) + 2) + Tv[U].z;                         \
    UQ.w = RL(av, 4 * (U) + 3) + Tv[U].w;                         \
    MQ = fmaxf(fmaxf(UQ.x, UQ.y), fmaxf(UQ.z, UQ.w));

#define SCAN_LO(U, UQ)                                            \
    lo |= (UQ.x == best) ? (1u << (4 * (U) + 0)) : 0u;            \
    lo |= (UQ.y == best) ? (1u << (4 * (U) + 1)) : 0u;            \
    lo |= (UQ.z == best) ? (1u << (4 * (U) + 2)) : 0u;            \
    lo |= (UQ.w == best) ? (1u << (4 * (U) + 3)) : 0u;

#define SCAN_HI(U, UQ)                                            \
    hi |= (UQ.x == best) ? (1u << (4 * (U) - 32)) : 0u;           \
    hi |= (UQ.y == best) ? (1u << (4 * (U) - 31)) : 0u;           \
    hi |= (UQ.z == best) ? (1u << (4 * (U) - 30)) : 0u;           \
    hi |= (UQ.w == best) ? (1u << (4 * (U) - 29)) : 0u;

#define VIT_BODY(T, BMV)                                             \
    {                                                                \
      const int t = (T);                                             \
      const float emit = em0;                                        \
      em0 = em1;                                                     \
      if (t + 2 < T_) em1 = scores[sb + (size_t)(t + 2) * 50 + kc];  \
      const int mt = (int)(((BMV) >> (t & 63)) & 1ull);              \
      VIT_Q(0, u0, q0)  VIT_Q(1, u1, q1)   VIT_Q(2, u2, q2)          \
      VIT_Q(3, u3, q3)  VIT_Q(4, u4, q4)   VIT_Q(5, u5, q5)          \
      VIT_Q(6, u6, q6)  VIT_Q(7, u7, q7)   VIT_Q(8, u8, q8)          \
      VIT_Q(9, u9, q9)  VIT_Q(10, u10, q10) VIT_Q(11, u11, q11)      \
      VIT_Q(12, u12, q12)                                            \
      const float h0 = fmaxf(q0, q1);                                \
      const float h1 = fmaxf(q2, q3);                                \
      const float h2 = fmaxf(q4, q5);                                \
      const float h3 = fmaxf(q6, q7);                                \
      const float h4 = fmaxf(q8, q9);                                \
      const float h5 = fmaxf(q10, q11);                              \
      const float best = fmaxf(fmaxf(fmaxf(h0, h1), fmaxf(h2, h3)),  \
                               fmaxf(fmaxf(h4, h5), q12));           \
      unsigned lo = 0u, hi = 0u;                                     \
      SCAN_LO(0, u0) SCAN_LO(1, u1) SCAN_LO(2, u2) SCAN_LO(3, u3)    \
      SCAN_LO(4, u4) SCAN_LO(5, u5) SCAN_LO(6, u6) SCAN_LO(7, u7)    \
      SCAN_HI(8, u8) SCAN_HI(9, u9) SCAN_HI(10, u10) SCAN_HI(11, u11)\
      SCAN_HI(12, u12)                                               \
      const int bj = (lo != 0u) ? __builtin_ctz(lo)                  \
                                : 32 + __builtin_ctz(hi);            \
      if (k < 50) bp_s[(t - 1) * 52 + k] = (unsigned char)(mt ? bj : k); \
      av = (mt && k < 50) ? (best + emit) : av;                      \
    }

#define VIT_PHASE(P, BMV, T0)                       \
    _Pragma("unroll 1")                             \
    for (int tt = (T0); tt < 64; ++tt) {            \
      VIT_BODY((P) * 64 + tt, BMV)                  \
    }

    VIT_PHASE(0, bm0, 1)
    VIT_PHASE(1, bm1, 0)
    VIT_PHASE(2, bm2, 0)
    VIT_PHASE(3, bm3, 0)
    VIT_PHASE(4, bm4, 0)
    VIT_PHASE(5, bm5, 0)
    VIT_PHASE(6, bm6, 0)
    VIT_PHASE(7, bm7, 0)

    float x = (k < 50) ? (av + endT[k]) : -3e38f;
    int xi = (k < 50) ? k : 63;
#pragma unroll
    for (int off = 32; off >= 1; off >>= 1) {
      const float ov = __shfl_xor(x, off);
      const int oi = __shfl_xor(xi, off);
      if (ov > x || (ov == x && oi < xi)) { x = ov; xi = oi; }
    }
    const int last = xi;  // butterfly converges: all lanes agree
    __syncthreads();
    // phase A: compose 16-step chunk maps; 25 jobs/lane = 6 groups of 4 + 1,
    // 4 independent walks interleaved to overlap LDS latency.
#pragma unroll 1
    for (int g = 0; g < 6; ++g) {
      const int iA = lane + 64 * (4 * g + 0);
      const int iB = lane + 64 * (4 * g + 1);
      const int iC = lane + 64 * (4 * g + 2);
      const int iD = lane + 64 * (4 * g + 3);
      const int cA = iA / 50, sA = iA - 50 * cA;
      const int cB = iB / 50, sB = iB - 50 * cB;
      const int cC = iC / 50, sC = iC - 50 * cC;
      const int cD = iD / 50, sD = iD - 50 * cD;
      int xA = sA, xB = sB, xC = sC, xD = sD;
#pragma unroll 1
      for (int i = 15; i >= 0; --i) {  // groups cover idx<1536 -> c<=30, rows<=510
        xA = bp_s[(16 * cA + i) * 52 + xA];
        xB = bp_s[(16 * cB + i) * 52 + xB];
        xC = bp_s[(16 * cC + i) * 52 + xC];
        xD = bp_s[(16 * cD + i) * 52 + xD];
      }
      g_s[cA * 52 + sA] = (unsigned char)xA;
      g_s[cB * 52 + sB] = (unsigned char)xB;
      g_s[cC * 52 + sC] = (unsigned char)xC;
      g_s[cD * 52 + sD] = (unsigned char)xD;
    }
    {
      const int iE = lane + 1536;
      const int cE = iE / 50, sE = iE - 50 * cE;
      int xE = sE;
#pragma unroll 1
      for (int i = 15; i >= 0; --i) {
        const int r = 16 * cE + i;
        if (r <= 510) xE = bp_s[r * 52 + xE];
      }
      g_s[cE * 52 + sE] = (unsigned char)xE;
    }
    __syncthreads();
    // phase B: serial chunk-boundary walk
    if (lane == 0) {
      int cur = last;
      chin_s[31] = (unsigned char)cur;
      for (int c = 31; c >= 1; --c) {
        cur = g_s[c * 52 + cur];
        chin_s[c - 1] = (unsigned char)cur;
      }
      const int m511 = mask[bT + 511];
      tagsOut[(size_t)bT + 511] = (float)((m511 > 0) ? last : 0);
    }
    __syncthreads();
    // phase C: per-chunk backtrace + tag stores
    if (lane < 32) {
      const int c = lane;
      int x3 = chin_s[c];
      const int lo2 = 16 * c;
      const int hi2 = min(16 * c + 15, 510);
      for (int i = hi2; i >= lo2; --i) {
        x3 = bp_s[i * 52 + x3];
        const int mi = mask[bT + i];
        tagsOut[(size_t)bT + i] = (float)((mi > 0) ? x3 : 0);
      }
    }
  } else {
    // ================= gold score =================
    float part = 0.f;
    int mcnt = 0;
#pragma unroll
    for (int s = 0; s < 8; s++) {
      const int t = lane + 64 * s;
      const int lt = labels[bT + t];
      const int mt = mask[bT + t];
      mcnt += mt;
      if (mt > 0) part += scores[sb + (size_t)t * 50 + lt];
      if (t < T_ - 1) {
        const int ln = labels[bT + t + 1];
        const int mn = mask[bT + t + 1];
        if (mn > 0) part += trans[lt * 50 + ln];
      }
    }
#pragma unroll
    for (int off = 32; off >= 1; off >>= 1) {
      part += __shfl_xor(part, off);
      mcnt += __shfl_xor(mcnt, off);
    }
    if (lane == 0) {
      const int l0 = labels[bT];
      const int llast = labels[bT + (mcnt - 1)];
      const float gold = part + startT[l0] + endT[llast];
      atomicAdd(lossSlot, -gold);
    }
  }
}

// ---------------------------------------------------------------------------
extern "C" void kernel_launch(void* const* d_in, const int* in_sizes, int n_in,
                              void* d_out, int out_size, void* d_ws, size_t ws_size,
                              hipStream_t stream) {
  const float* inputs = (const float*)d_in[0];
  const int* mask = (const int*)d_in[1];
  const int* labels = (const int*)d_in[2];
  const float* W = (const float*)d_in[3];
  const float* bias = (const float*)d_in[4];
  const float* trans = (const float*)d_in[5];
  const float* startT = (const float*)d_in[6];
  const float* endT = (const float*)d_in[7];

  float* out = (float*)d_out;
  float* scores = out;
  float* tagsOut = out + (size_t)B_ * T_ * K_;
  float* lossSlot = out + (size_t)B_ * T_ * K_ + B_ * T_;
  float* Pws = (float*)d_ws;

  const size_t per = (size_t)K_ * MROWS * sizeof(float);  // 6.55 MB
  const int SK = (ws_size >= 3 * per) ? 4 : 2;            // ws holds SK-1 partials
  const int chunkK = D_ / SK;

  dim3 g1(MROWS / 128, SK);
  gemm_kernel<<<g1, 256, 0, stream>>>(inputs, W, scores, Pws, chunkK);

  combine_kernel<<<(K_ * MROWS) / 256, 256, 0, stream>>>(Pws, SK - 1, bias, mask,
                                                         scores, lossSlot);

  dim3 g3(B_, 3);
  crf_kernel<<<g3, 64, 0, stream>>>(scores, mask, labels, trans, startT, endT,
                                    tagsOut, lossSlot);
}